// Round 6
// baseline (4533.331 us; speedup 1.0000x reference)
//
#include <hip/hip_runtime.h>
#include <hip/hip_bf16.h>

typedef unsigned int u32;
typedef _Float16 h2 __attribute__((ext_vector_type(2)));

__device__ __forceinline__ float fdot2(u32 a, u32 b, float c) {
    return __builtin_amdgcn_fdot2(__builtin_bit_cast(h2, a),
                                  __builtin_bit_cast(h2, b), c, false);
}
__device__ __forceinline__ u32 pk(float a, float b) {
    return __builtin_bit_cast(u32, __builtin_amdgcn_cvt_pkrtz(a, b));
}
__device__ __forceinline__ float lo16(u32 v) { h2 h = __builtin_bit_cast(h2, v); return (float)h[0]; }
__device__ __forceinline__ float hi16(u32 v) { h2 h = __builtin_bit_cast(h2, v); return (float)h[1]; }

// ---------------------------------------------------------------------------
// Pack weights into f16x2 channel/K pairs.
//   w2p[oc][ic2=16][9], w3p[oc][ic2=32][9], wp1[j=128][u=6272]
// ---------------------------------------------------------------------------
__global__ __launch_bounds__(256) void k_pack(const float* __restrict__ w2,
                                              const float* __restrict__ w3,
                                              const float* __restrict__ fw1,
                                              u32* w2p, u32* w3p, u32* wp1) {
    int i = blockIdx.x * 256 + threadIdx.x;
    const int n1 = 64 * 16 * 9, n2 = 64 * 32 * 9, n3 = 128 * 6272;
    if (i < n1) {
        int oc = i / 144, r = i % 144, ic2 = r / 9, tap = r % 9;
        w2p[i] = pk(w2[(oc * 32 + 2 * ic2) * 9 + tap],
                    w2[(oc * 32 + 2 * ic2 + 1) * 9 + tap]);
    } else if (i < n1 + n2) {
        int j = i - n1;
        int oc = j / 288, r = j % 288, ic2 = r / 9, tap = r % 9;
        w3p[j] = pk(w3[(oc * 64 + 2 * ic2) * 9 + tap],
                    w3[(oc * 64 + 2 * ic2 + 1) * 9 + tap]);
    } else if (i < n1 + n2 + n3) {
        int j = i - n1 - n2;
        int row = j / 6272, u = j % 6272;
        wp1[j] = pk(fw1[row * 12544 + 2 * u], fw1[row * 12544 + 2 * u + 1]);
    }
}

// ---------------------------------------------------------------------------
// Fused conv1+IN+ReLU + conv2+IN + conv3+ReLU+maxpool. One block per image.
// LDS: B region (25088 u32 = conv1 f32 out, then conv2 pairs)
//      A region (14400 u32 = padded input f32 early, then padded conv1 pairs)
//      st (128 f32 stats). Total 158,464 B.
// Output: pflat[b][oc*98 + u] pooled f16 pairs (flatten k = oc*196 + s).
// ---------------------------------------------------------------------------
__global__ __launch_bounds__(256) void k_net(const float* __restrict__ x,
                                             const float* __restrict__ w1,
                                             const float* __restrict__ b1,
                                             const u32* __restrict__ w2p,
                                             const float* __restrict__ b2,
                                             const u32* __restrict__ w3p,
                                             const float* __restrict__ b3,
                                             u32* __restrict__ pflat) {
    __shared__ u32 smem[25088 + 14400 + 128];
    u32* Breg  = smem;                         // 25088 u32 / 25088 f32
    float* c1f = (float*)smem;
    u32* a1    = smem + 25088;                 // 14400 u32 (16 x 900 padded pairs)
    float* xs  = (float*)(smem + 25088);       // 900 f32 (aliases a1; earlier phase)
    float* st  = (float*)(smem + 25088 + 14400);

    const int b = blockIdx.x, t = threadIdx.x;
    const int wv = t >> 6, lane = t & 63;

    // ---- stage input (zero-padded 30x30)
    for (int i = t; i < 900; i += 256) xs[i] = 0.f;
    __syncthreads();
    const float* xb = x + b * 784;
    for (int i = t; i < 784; i += 256) xs[(i / 28 + 1) * 30 + (i % 28) + 1] = xb[i];
    __syncthreads();

    // ---- conv1 -> c1f (f32)
    for (int oc = 0; oc < 32; ++oc) {
        float w[9];
#pragma unroll
        for (int k = 0; k < 9; ++k) w[k] = w1[oc * 9 + k];
        float bias = b1[oc];
        for (int p = t; p < 784; p += 256) {
            const float* base = &xs[(p / 28) * 30 + (p % 28)];
            float acc = bias;
#pragma unroll
            for (int r = 0; r < 3; ++r)
#pragma unroll
                for (int c = 0; c < 3; ++c) acc += base[r * 30 + c] * w[3 * r + c];
            c1f[oc * 784 + p] = acc;
        }
    }
    __syncthreads();

    // ---- conv1 IN stats (32 ch)
    for (int oc = wv; oc < 32; oc += 4) {
        float s = 0.f, s2 = 0.f;
        for (int p = lane; p < 784; p += 64) { float v = c1f[oc * 784 + p]; s += v; s2 += v * v; }
#pragma unroll
        for (int off = 32; off; off >>= 1) { s += __shfl_xor(s, off); s2 += __shfl_xor(s2, off); }
        if (lane == 0) {
            float mu = s * (1.f / 784.f);
            float var = s2 * (1.f / 784.f) - mu * mu;
            st[2 * oc] = mu; st[2 * oc + 1] = rsqrtf(var + 1e-5f);
        }
    }
    __syncthreads();

    // ---- normalize+relu+pack -> padded a1 (xs dead; reads c1f)
    for (int i = t; i < 14400; i += 256) {
        int ic2 = i / 900, pp = i % 900, y = pp / 30 - 1, xx = pp % 30 - 1;
        u32 v = 0u;
        if ((unsigned)y < 28u && (unsigned)xx < 28u) {
            int p = y * 28 + xx;
            float f0 = (c1f[(2 * ic2) * 784 + p]     - st[4 * ic2])     * st[4 * ic2 + 1];
            float f1 = (c1f[(2 * ic2 + 1) * 784 + p] - st[4 * ic2 + 2]) * st[4 * ic2 + 3];
            v = pk(fmaxf(f0, 0.f), fmaxf(f1, 0.f));
        }
        a1[i] = v;
    }
    __syncthreads();

    const bool act = t < 196;
    const int y0 = (t / 14) * 2, x0 = (t % 14) * 2;

    // ---- conv2: read padded a1, write RAW f16 pairs into Breg (c1f dead)
    if (act) {
#pragma unroll 1
        for (int half = 0; half < 2; ++half) {
            float acc[8][4][4];
#pragma unroll
            for (int g = 0; g < 8; ++g)
#pragma unroll
                for (int o = 0; o < 4; ++o) {
                    float bias = b2[(half * 8 + g) * 4 + o];
#pragma unroll
                    for (int q = 0; q < 4; ++q) acc[g][o][q] = bias;
                }
#pragma unroll 1
            for (int ic2 = 0; ic2 < 16; ++ic2) {
                u32 in[4][4];
                const u32* base = &a1[ic2 * 900 + y0 * 30 + x0];
#pragma unroll
                for (int r = 0; r < 4; ++r)
#pragma unroll
                    for (int c = 0; c < 4; ++c) in[r][c] = base[r * 30 + c];
#pragma unroll
                for (int g = 0; g < 8; ++g)
#pragma unroll
                    for (int o = 0; o < 4; ++o) {
                        const u32* wo = &w2p[(((half * 8 + g) * 4 + o) * 16 + ic2) * 9];
#pragma unroll
                        for (int dy = 0; dy < 3; ++dy)
#pragma unroll
                            for (int dx = 0; dx < 3; ++dx) {
                                u32 wvv = wo[dy * 3 + dx];
#pragma unroll
                                for (int py = 0; py < 2; ++py)
#pragma unroll
                                    for (int px = 0; px < 2; ++px)
                                        acc[g][o][py * 2 + px] =
                                            fdot2(in[py + dy][px + dx], wvv, acc[g][o][py * 2 + px]);
                            }
                    }
            }
#pragma unroll
            for (int g = 0; g < 8; ++g) {
                int gg = half * 8 + g;
#pragma unroll
                for (int py = 0; py < 2; ++py)
#pragma unroll
                    for (int px = 0; px < 2; ++px) {
                        int pix = (y0 + py) * 28 + (x0 + px);
                        int q = py * 2 + px;
                        Breg[(2 * gg) * 784 + pix]     = pk(acc[g][0][q], acc[g][1][q]);
                        Breg[(2 * gg + 1) * 784 + pix] = pk(acc[g][2][q], acc[g][3][q]);
                    }
            }
        }
    }
    __syncthreads();

    // ---- conv2 IN stats (64 ch) from packed pairs
    for (int ch = wv; ch < 64; ch += 4) {
        float s = 0.f, s2 = 0.f;
        const u32* row = &Breg[(ch >> 1) * 784];
        for (int p = lane; p < 784; p += 64) {
            u32 v = row[p];
            float f = (ch & 1) ? hi16(v) : lo16(v);
            s += f; s2 += f * f;
        }
#pragma unroll
        for (int off = 32; off; off >>= 1) { s += __shfl_xor(s, off); s2 += __shfl_xor(s2, off); }
        if (lane == 0) {
            float mu = s * (1.f / 784.f);
            float var = s2 * (1.f / 784.f) - mu * mu;
            st[2 * ch] = mu; st[2 * ch + 1] = rsqrtf(var + 1e-5f);
        }
    }
    __syncthreads();

    // ---- normalize conv2 pairs in place
    for (int i = t; i < 25088; i += 256) {
        int pr = i / 784;
        float mu0 = st[4 * pr], ri0 = st[4 * pr + 1];
        float mu1 = st[4 * pr + 2], ri1 = st[4 * pr + 3];
        u32 v = Breg[i];
        Breg[i] = pk((lo16(v) - mu0) * ri0, (hi16(v) - mu1) * ri1);
    }
    __syncthreads();

    // ---- conv3 + relu + maxpool -> pflat (reads Breg unpadded, masked edges)
    if (act) {
        int off[4][4];
        bool ok[4][4];
#pragma unroll
        for (int r = 0; r < 4; ++r)
#pragma unroll
            for (int c = 0; c < 4; ++c) {
                int y = y0 - 1 + r, xx = x0 - 1 + c;
                ok[r][c] = ((unsigned)y < 28u) && ((unsigned)xx < 28u);
                int yc = y < 0 ? 0 : (y > 27 ? 27 : y);
                int xc = xx < 0 ? 0 : (xx > 27 ? 27 : xx);
                off[r][c] = yc * 28 + xc;
            }
        u32* dst = pflat + b * 6272;
#pragma unroll 1
        for (int half = 0; half < 2; ++half) {
            float acc[8][4][4];
#pragma unroll
            for (int g = 0; g < 8; ++g)
#pragma unroll
                for (int o = 0; o < 4; ++o) {
                    float bias = b3[(half * 8 + g) * 4 + o];
#pragma unroll
                    for (int q = 0; q < 4; ++q) acc[g][o][q] = bias;
                }
#pragma unroll 1
            for (int ic2 = 0; ic2 < 32; ++ic2) {
                u32 in[4][4];
                const u32* base = &Breg[ic2 * 784];
#pragma unroll
                for (int r = 0; r < 4; ++r)
#pragma unroll
                    for (int c = 0; c < 4; ++c) {
                        u32 raw = base[off[r][c]];
                        in[r][c] = ok[r][c] ? raw : 0u;
                    }
#pragma unroll
                for (int g = 0; g < 8; ++g)
#pragma unroll
                    for (int o = 0; o < 4; ++o) {
                        const u32* wo = &w3p[(((half * 8 + g) * 4 + o) * 32 + ic2) * 9];
#pragma unroll
                        for (int dy = 0; dy < 3; ++dy)
#pragma unroll
                            for (int dx = 0; dx < 3; ++dx) {
                                u32 wvv = wo[dy * 3 + dx];
#pragma unroll
                                for (int py = 0; py < 2; ++py)
#pragma unroll
                                    for (int px = 0; px < 2; ++px)
                                        acc[g][o][py * 2 + px] =
                                            fdot2(in[py + dy][px + dx], wvv, acc[g][o][py * 2 + px]);
                            }
                    }
            }
#pragma unroll
            for (int g = 0; g < 8; ++g) {
                int oc4 = (half * 8 + g) * 4;
#pragma unroll
                for (int o = 0; o < 4; ++o) {
                    float m = fmaxf(fmaxf(acc[g][o][0], acc[g][o][1]),
                                    fmaxf(acc[g][o][2], acc[g][o][3]));
                    m = fmaxf(m, 0.f);              // relu(max) == max(relu)
                    float partner = __shfl_xor(m, 1);
                    if ((t & 1) == 0)
                        dst[(oc4 + o) * 98 + (t >> 1)] = pk(m, partner);
                }
            }
        }
    }
}

// ---------------------------------------------------------------------------
// FC1 partial GEMM: part[kb][img][j], K-split by 8 (784 pairs each).
// ---------------------------------------------------------------------------
__global__ __launch_bounds__(256) void k_fc1(const u32* __restrict__ pflat,
                                             const u32* __restrict__ wp1,
                                             float* __restrict__ part) {
    int mb = blockIdx.x, kb = blockIdx.y, t = threadIdx.x;
    __shared__ u32 Ps[64][60];
    __shared__ u32 Ws[128][60];
    float acc[4][8];
#pragma unroll
    for (int a = 0; a < 4; ++a)
#pragma unroll
        for (int c = 0; c < 8; ++c) acc[a][c] = 0.f;
    int im0 = (t / 16) * 4, j0 = (t % 16) * 8;
    int k0 = kb * 784;
    for (int kc = 0; kc < 784; kc += 56) {
        for (int i = t; i < 64 * 56; i += 256) {
            int img = i / 56, kp = i % 56;
            Ps[img][kp] = pflat[(mb * 64 + img) * 6272 + k0 + kc + kp];
        }
        for (int i = t; i < 128 * 56; i += 256) {
            int row = i / 56, kp = i % 56;
            Ws[row][kp] = wp1[row * 6272 + k0 + kc + kp];
        }
        __syncthreads();
        for (int kp = 0; kp < 56; ++kp) {
            u32 pv[4], wvv[8];
#pragma unroll
            for (int a = 0; a < 4; ++a) pv[a] = Ps[im0 + a][kp];
#pragma unroll
            for (int c = 0; c < 8; ++c) wvv[c] = Ws[j0 + c][kp];
#pragma unroll
            for (int a = 0; a < 4; ++a)
#pragma unroll
                for (int c = 0; c < 8; ++c)
                    acc[a][c] = fdot2(pv[a], wvv[c], acc[a][c]);
        }
        __syncthreads();
    }
#pragma unroll
    for (int a = 0; a < 4; ++a)
#pragma unroll
        for (int c = 0; c < 8; ++c)
            part[kb * (2048 * 128) + (mb * 64 + im0 + a) * 128 + (j0 + c)] = acc[a][c];
}

// ---------------------------------------------------------------------------
// Reduce partials + bias + ReLU -> FC2 -> log_softmax.
// ---------------------------------------------------------------------------
__global__ __launch_bounds__(256) void k_fc2(const float* __restrict__ part,
                                             const float* __restrict__ fb1,
                                             const float* __restrict__ fw2,
                                             const float* __restrict__ fb2,
                                             float* __restrict__ out) {
    int mb = blockIdx.x, t = threadIdx.x;
    __shared__ float h[64 * 128];
    __shared__ float lg[64 * 10];
    for (int i = t; i < 64 * 128; i += 256) {
        int img = i / 128, j = i % 128;
        float s = fb1[j];
#pragma unroll
        for (int kb = 0; kb < 8; ++kb)
            s += part[kb * (2048 * 128) + (mb * 64 + img) * 128 + j];
        h[i] = s > 0.f ? s : 0.f;
    }
    __syncthreads();
    for (int i = t; i < 640; i += 256) {
        int img = i / 10, c = i % 10;
        float s = fb2[c];
        for (int j = 0; j < 128; ++j) s += h[img * 128 + j] * fw2[c * 128 + j];
        lg[i] = s;
    }
    __syncthreads();
    if (t < 64) {
        float m = -1e30f;
        for (int c = 0; c < 10; ++c) m = fmaxf(m, lg[t * 10 + c]);
        float s = 0.f;
        for (int c = 0; c < 10; ++c) s += expf(lg[t * 10 + c] - m);
        float ls = logf(s);
        for (int c = 0; c < 10; ++c)
            out[(mb * 64 + t) * 10 + c] = lg[t * 10 + c] - m - ls;
    }
}

// ---------------------------------------------------------------------------
extern "C" void kernel_launch(void* const* d_in, const int* in_sizes, int n_in,
                              void* d_out, int out_size, void* d_ws, size_t ws_size,
                              hipStream_t stream) {
    const float* x   = (const float*)d_in[0];
    const float* w1  = (const float*)d_in[1];
    const float* b1  = (const float*)d_in[2];
    const float* w2  = (const float*)d_in[3];
    const float* b2  = (const float*)d_in[4];
    const float* w3  = (const float*)d_in[5];
    const float* b3  = (const float*)d_in[6];
    const float* fw1 = (const float*)d_in[7];
    const float* fb1 = (const float*)d_in[8];
    const float* fw2 = (const float*)d_in[9];
    const float* fb2 = (const float*)d_in[10];
    float* out = (float*)d_out;

    // ws layout (4-byte units): total ~63 MB
    const size_t PFL  = (size_t)2048 * 6272;     // 12,845,056
    const size_t PART = (size_t)8 * 2048 * 128;  //  2,097,152
    const size_t W2P = 64 * 16 * 9, W3P = 64 * 32 * 9, WP1 = (size_t)128 * 6272;

    u32* ws = (u32*)d_ws;
    u32* pflat  = ws;
    float* part = (float*)(pflat + PFL);
    u32* w2p    = (u32*)(part + PART);
    u32* w3p    = w2p + W2P;
    u32* wp1    = w3p + W3P;

    const int n_pack = (int)(W2P + W3P + WP1);
    k_pack<<<(n_pack + 255) / 256, 256, 0, stream>>>(w2, w3, fw1, w2p, w3p, wp1);
    k_net<<<2048, 256, 0, stream>>>(x, w1, b1, w2p, b2, w3p, b3, pflat);
    k_fc1<<<dim3(32, 8), 256, 0, stream>>>(pflat, wp1, part);
    k_fc2<<<32, 256, 0, stream>>>(part, fb1, fw2, fb2, out);
}

// Round 7
// 1343.546 us; speedup vs baseline: 3.3742x; 3.3742x over previous
//
#include <hip/hip_runtime.h>
#include <hip/hip_bf16.h>

typedef unsigned int u32;
typedef _Float16 h2 __attribute__((ext_vector_type(2)));
typedef _Float16 f16x8 __attribute__((ext_vector_type(8)));
typedef float f32x4 __attribute__((ext_vector_type(4)));
typedef u32 u32x4 __attribute__((ext_vector_type(4)));

__device__ __forceinline__ float fdot2(u32 a, u32 b, float c) {
    return __builtin_amdgcn_fdot2(__builtin_bit_cast(h2, a),
                                  __builtin_bit_cast(h2, b), c, false);
}
__device__ __forceinline__ u32 pk(float a, float b) {
    return __builtin_bit_cast(u32, __builtin_amdgcn_cvt_pkrtz(a, b));
}
__device__ __forceinline__ float lo16(u32 v) { h2 h = __builtin_bit_cast(h2, v); return (float)h[0]; }
__device__ __forceinline__ float hi16(u32 v) { h2 h = __builtin_bit_cast(h2, v); return (float)h[1]; }

// LDS layout (u32 indices)
#define A1O   0        // a1cl [784][16] u32  (conv1 packed ch-last, swizzled)
#define A2O   12544    // a2cl [784][32] u32  (conv2 packed ch-last, swizzled) +16 guard
#define STO   37648    // stats 128 f32
#define SB2O  37776    // bias2 64 f32
#define SB3O  37840    // bias3 64 f32
#define SMEMSZ 37904   // 151,616 B

// ---------------------------------------------------------------------------
// k_pack: weights into MFMA A-fragment order + FC1 f16 pairs.
// wA2[(mt*9+ks)*64+l][r]: A[oc=mt*16+(l&15)][k=ks*32+(l>>4)*8+2r(+1)], k=tap*32+ic
// wA3[(mt*18+ks)*64+l][r]: k=tap*64+ic, tap=ks>>1, ic=(ks&1)*32+(l>>4)*8+2r(+1)
// wp1[row][u]: pairs (2u,2u+1) of flattened fw1 row.
// ---------------------------------------------------------------------------
__global__ __launch_bounds__(256) void k_pack(const float* __restrict__ w2,
                                              const float* __restrict__ w3,
                                              const float* __restrict__ fw1,
                                              u32* wA2, u32* wA3, u32* wp1) {
    int i = blockIdx.x * 256 + threadIdx.x;
    const int n1 = 9216, n2 = 18432, n3 = 128 * 6272;
    if (i < n1) {
        int r = i & 3, l = (i >> 2) & 63, t2 = i >> 8;   // t2 = mt*9+ks
        int ks = t2 % 9, mt = t2 / 9;
        int oc = mt * 16 + (l & 15);
        int ic = (l >> 4) * 8 + 2 * r;
        wA2[i] = pk(w2[(oc * 32 + ic) * 9 + ks], w2[(oc * 32 + ic + 1) * 9 + ks]);
    } else if (i < n1 + n2) {
        int j = i - n1;
        int r = j & 3, l = (j >> 2) & 63, t2 = j >> 8;   // t2 = mt*18+ks
        int ks = t2 % 18, mt = t2 / 18;
        int oc = mt * 16 + (l & 15);
        int ic = (ks & 1) * 32 + (l >> 4) * 8 + 2 * r;
        int tap = ks >> 1;
        wA3[j] = pk(w3[(oc * 64 + ic) * 9 + tap], w3[(oc * 64 + ic + 1) * 9 + tap]);
    } else if (i < n1 + n2 + n3) {
        int j = i - n1 - n2;
        int row = j / 6272, u = j % 6272;
        wp1[j] = pk(fw1[row * 12544 + 2 * u], fw1[row * 12544 + 2 * u + 1]);
    }
}

// ---------------------------------------------------------------------------
// Fused net1: conv1+IN+ReLU (VALU) -> conv2 (MFMA) + IN -> conv3 (MFMA)
// + ReLU + maxpool. One block per image. Output u16 f16 at flatten order
// k = oc*196 + r*14 + px.
// ---------------------------------------------------------------------------
__global__ __launch_bounds__(256) void k_net(const float* __restrict__ x,
                                             const float* __restrict__ w1,
                                             const float* __restrict__ b1,
                                             const u32* __restrict__ wA2,
                                             const float* __restrict__ b2,
                                             const u32* __restrict__ wA3,
                                             const float* __restrict__ b3,
                                             u32* __restrict__ pflat) {
    __shared__ u32 smem[SMEMSZ];
    u32* a1 = smem + A1O;
    u32* a2 = smem + A2O;
    float* st  = (float*)(smem + STO);
    float* sb2 = (float*)(smem + SB2O);
    float* sb3 = (float*)(smem + SB3O);
    float* xs  = (float*)(smem + A1O);     // 900 f32, early phase only
    float* c1f = (float*)(smem + A2O);     // 32*784 f32, early phase only

    const int b = blockIdx.x, t = threadIdx.x;
    const int wv = t >> 6, l = t & 63;
    const int xi = l & 15, kg = l >> 4;

    // ---- phase 0: biases + zero padded input
    if (t < 64) { sb2[t] = b2[t]; sb3[t] = b3[t]; }
    for (int i = t; i < 900; i += 256) xs[i] = 0.f;
    __syncthreads();
    // ---- phase 1: stage input
    const float* xb = x + b * 784;
    for (int i = t; i < 784; i += 256) xs[(i / 28 + 1) * 30 + (i % 28) + 1] = xb[i];
    __syncthreads();
    // ---- phase 2: conv1 (VALU) -> c1f[32][784]
    for (int oc = 0; oc < 32; ++oc) {
        float w[9];
#pragma unroll
        for (int k = 0; k < 9; ++k) w[k] = w1[oc * 9 + k];
        float bias = b1[oc];
        for (int p = t; p < 784; p += 256) {
            const float* base = &xs[(p / 28) * 30 + (p % 28)];
            float acc = bias;
#pragma unroll
            for (int r = 0; r < 3; ++r)
#pragma unroll
                for (int c = 0; c < 3; ++c) acc += base[r * 30 + c] * w[3 * r + c];
            c1f[oc * 784 + p] = acc;
        }
    }
    __syncthreads();
    // ---- phase 3: conv1 IN stats
    for (int oc = wv; oc < 32; oc += 4) {
        float s = 0.f, s2 = 0.f;
        for (int p = l; p < 784; p += 64) { float v = c1f[oc * 784 + p]; s += v; s2 += v * v; }
#pragma unroll
        for (int off = 32; off; off >>= 1) { s += __shfl_xor(s, off); s2 += __shfl_xor(s2, off); }
        if (l == 0) {
            float mu = s * (1.f / 784.f);
            float var = s2 * (1.f / 784.f) - mu * mu;
            st[2 * oc] = mu; st[2 * oc + 1] = rsqrtf(var + 1e-5f);
        }
    }
    __syncthreads();
    // ---- phase 4: normalize+relu+pack -> a1cl[p*16 + (cp ^ SW1(p))]
    for (int i = t; i < 12544; i += 256) {
        int cp = i / 784, p = i % 784;
        float f0 = (c1f[(2 * cp) * 784 + p]     - st[4 * cp])     * st[4 * cp + 1];
        float f1 = (c1f[(2 * cp + 1) * 784 + p] - st[4 * cp + 2]) * st[4 * cp + 3];
        a1[p * 16 + (cp ^ (((p >> 1) & 3) << 2))] = pk(fmaxf(f0, 0.f), fmaxf(f1, 0.f));
    }
    __syncthreads();

    // ---- phase 5: conv2 MFMA. 56 n-tiles (28y x 2 halves); wave: 14 tiles as
    // 7 same-y pairs. Writes raw f16 pairs to a2cl (c1f dead).
    {
        for (int c7 = 0; c7 < 7; ++c7) {
            int nt = wv * 14 + c7 * 2;       // even: (y, h=0),(y, h=1)
            int y = nt >> 1;
            f32x4 acc[2][4];
#pragma unroll
            for (int hs = 0; hs < 2; ++hs)
#pragma unroll
                for (int mt = 0; mt < 4; ++mt) {
#pragma unroll
                    for (int r = 0; r < 4; ++r) acc[hs][mt][r] = sb2[mt * 16 + kg * 4 + r];
                }
#pragma unroll 2
            for (int ks = 0; ks < 9; ++ks) {
                int dy = ks / 3, dx = ks % 3;
                int yy = y + dy - 1;
                if ((unsigned)yy >= 28u) continue;
                u32x4 af[4];
#pragma unroll
                for (int mt = 0; mt < 4; ++mt)
                    af[mt] = *(const u32x4*)(wA2 + (((mt * 9 + ks) * 64 + l) << 2));
#pragma unroll
                for (int hs = 0; hs < 2; ++hs) {
                    int xx = hs * 16 + xi + dx - 1;
                    int ax = xx < 0 ? 0 : (xx > 27 ? 27 : xx);
                    bool mk = (unsigned)xx < 28u;
                    int pp = yy * 28 + ax;
                    u32x4 bv = *(const u32x4*)&a1[pp * 16 + ((kg * 4) ^ (((pp >> 1) & 3) << 2))];
                    u32x4 z = {0u, 0u, 0u, 0u};
                    bv = mk ? bv : z;
#pragma unroll
                    for (int mt = 0; mt < 4; ++mt)
                        acc[hs][mt] = __builtin_amdgcn_mfma_f32_16x16x32_f16(
                            __builtin_bit_cast(f16x8, af[mt]),
                            __builtin_bit_cast(f16x8, bv), acc[hs][mt], 0, 0, 0);
                }
            }
#pragma unroll
            for (int hs = 0; hs < 2; ++hs) {
                int xx = hs * 16 + xi;
                if (xx < 28) {
                    int p = y * 28 + xx;
                    int sw = (p & 7) << 2;
#pragma unroll
                    for (int mt = 0; mt < 4; ++mt) {
                        int cp0 = mt * 8 + kg * 2;
                        a2[p * 32 + (cp0 ^ sw)]       = pk(acc[hs][mt][0], acc[hs][mt][1]);
                        a2[p * 32 + ((cp0 + 1) ^ sw)] = pk(acc[hs][mt][2], acc[hs][mt][3]);
                    }
                }
            }
        }
    }
    __syncthreads();
    // ---- phase 6: conv2 IN stats (64 ch)
    for (int ch = wv; ch < 64; ch += 4) {
        float s = 0.f, s2 = 0.f;
        int cp = ch >> 1, hi = ch & 1;
        for (int p = l; p < 784; p += 64) {
            u32 v = a2[p * 32 + (cp ^ ((p & 7) << 2))];
            float f = hi ? hi16(v) : lo16(v);
            s += f; s2 += f * f;
        }
#pragma unroll
        for (int off = 32; off; off >>= 1) { s += __shfl_xor(s, off); s2 += __shfl_xor(s2, off); }
        if (l == 0) {
            float mu = s * (1.f / 784.f);
            float var = s2 * (1.f / 784.f) - mu * mu;
            st[2 * ch] = mu; st[2 * ch + 1] = rsqrtf(var + 1e-5f);
        }
    }
    __syncthreads();
    // ---- phase 7: normalize a2cl in place (no relu)
    for (int i = t; i < 25088; i += 256) {
        int p = i >> 5, cp = i & 31;
        int idx = p * 32 + (cp ^ ((p & 7) << 2));
        u32 v = a2[idx];
        a2[idx] = pk((lo16(v) - st[4 * cp]) * st[4 * cp + 1],
                     (hi16(v) - st[4 * cp + 2]) * st[4 * cp + 3]);
    }
    __syncthreads();

    // ---- phase 8: conv3 MFMA on row-pairs + relu + maxpool -> u16 stores
    {
        unsigned short* dstp = (unsigned short*)pflat;
        for (int i7 = 0; i7 < 7; ++i7) {
            int pr = wv * 7 + i7;            // 0..27
            int r = pr >> 1, h = pr & 1;
            f32x4 acc[2][4];
#pragma unroll
            for (int sub = 0; sub < 2; ++sub)
#pragma unroll
                for (int mt = 0; mt < 4; ++mt) {
#pragma unroll
                    for (int rr = 0; rr < 4; ++rr) acc[sub][mt][rr] = sb3[mt * 16 + kg * 4 + rr];
                }
#pragma unroll 2
            for (int ks = 0; ks < 18; ++ks) {
                int tap = ks >> 1, kh = ks & 1;
                int dy = tap / 3, dx = tap % 3;
                u32x4 af[4];
#pragma unroll
                for (int mt = 0; mt < 4; ++mt)
                    af[mt] = *(const u32x4*)(wA3 + (((mt * 18 + ks) * 64 + l) << 2));
                int xx = h * 16 + xi + dx - 1;
                int ax = xx < 0 ? 0 : (xx > 27 ? 27 : xx);
                bool mk = (unsigned)xx < 28u;
#pragma unroll
                for (int sub = 0; sub < 2; ++sub) {
                    int yy = 2 * r + sub + dy - 1;
                    if ((unsigned)yy >= 28u) continue;
                    int pp = yy * 28 + ax;
                    u32x4 bv = *(const u32x4*)&a2[pp * 32 + ((kh * 16 + kg * 4) ^ ((pp & 7) << 2))];
                    u32x4 z = {0u, 0u, 0u, 0u};
                    bv = mk ? bv : z;
#pragma unroll
                    for (int mt = 0; mt < 4; ++mt)
                        acc[sub][mt] = __builtin_amdgcn_mfma_f32_16x16x32_f16(
                            __builtin_bit_cast(f16x8, af[mt]),
                            __builtin_bit_cast(f16x8, bv), acc[sub][mt], 0, 0, 0);
                }
            }
            // relu + 2x2 maxpool + store
#pragma unroll
            for (int mt = 0; mt < 4; ++mt)
#pragma unroll
                for (int rr = 0; rr < 4; ++rr) {
                    float v = fmaxf(acc[0][mt][rr], acc[1][mt][rr]);
                    v = fmaxf(v, 0.f);
                    float partner = __shfl_xor(v, 1);
                    float hx = fmaxf(v, partner);
                    int xx = h * 16 + xi;
                    if ((xi & 1) == 0 && xx < 28) {
                        int px = xx >> 1;
                        int oc = mt * 16 + kg * 4 + rr;
                        dstp[b * 12544 + oc * 196 + r * 14 + px] =
                            __builtin_bit_cast(unsigned short, (_Float16)hx);
                    }
                }
        }
    }
}

// ---------------------------------------------------------------------------
// FC1 partial GEMM: part[kb][img][j], K-split by 8 (784 pairs each).
// ---------------------------------------------------------------------------
__global__ __launch_bounds__(256) void k_fc1(const u32* __restrict__ pflat,
                                             const u32* __restrict__ wp1,
                                             float* __restrict__ part) {
    int mb = blockIdx.x, kb = blockIdx.y, t = threadIdx.x;
    __shared__ u32 Ps[64][60];
    __shared__ u32 Ws[128][60];
    float acc[4][8];
#pragma unroll
    for (int a = 0; a < 4; ++a)
#pragma unroll
        for (int c = 0; c < 8; ++c) acc[a][c] = 0.f;
    int im0 = (t / 16) * 4, j0 = (t % 16) * 8;
    int k0 = kb * 784;
    for (int kc = 0; kc < 784; kc += 56) {
        for (int i = t; i < 64 * 56; i += 256) {
            int img = i / 56, kp = i % 56;
            Ps[img][kp] = pflat[(mb * 64 + img) * 6272 + k0 + kc + kp];
        }
        for (int i = t; i < 128 * 56; i += 256) {
            int row = i / 56, kp = i % 56;
            Ws[row][kp] = wp1[row * 6272 + k0 + kc + kp];
        }
        __syncthreads();
        for (int kp = 0; kp < 56; ++kp) {
            u32 pv[4], wvv[8];
#pragma unroll
            for (int a = 0; a < 4; ++a) pv[a] = Ps[im0 + a][kp];
#pragma unroll
            for (int c = 0; c < 8; ++c) wvv[c] = Ws[j0 + c][kp];
#pragma unroll
            for (int a = 0; a < 4; ++a)
#pragma unroll
                for (int c = 0; c < 8; ++c)
                    acc[a][c] = fdot2(pv[a], wvv[c], acc[a][c]);
        }
        __syncthreads();
    }
#pragma unroll
    for (int a = 0; a < 4; ++a)
#pragma unroll
        for (int c = 0; c < 8; ++c)
            part[kb * (2048 * 128) + (mb * 64 + im0 + a) * 128 + (j0 + c)] = acc[a][c];
}

// ---------------------------------------------------------------------------
// Reduce partials + bias + ReLU -> FC2 -> log_softmax.
// ---------------------------------------------------------------------------
__global__ __launch_bounds__(256) void k_fc2(const float* __restrict__ part,
                                             const float* __restrict__ fb1,
                                             const float* __restrict__ fw2,
                                             const float* __restrict__ fb2,
                                             float* __restrict__ out) {
    int mb = blockIdx.x, t = threadIdx.x;
    __shared__ float h[64 * 128];
    __shared__ float lg[64 * 10];
    for (int i = t; i < 64 * 128; i += 256) {
        int img = i / 128, j = i % 128;
        float s = fb1[j];
#pragma unroll
        for (int kb = 0; kb < 8; ++kb)
            s += part[kb * (2048 * 128) + (mb * 64 + img) * 128 + j];
        h[i] = s > 0.f ? s : 0.f;
    }
    __syncthreads();
    for (int i = t; i < 640; i += 256) {
        int img = i / 10, c = i % 10;
        float s = fb2[c];
        for (int j = 0; j < 128; ++j) s += h[img * 128 + j] * fw2[c * 128 + j];
        lg[i] = s;
    }
    __syncthreads();
    if (t < 64) {
        float m = -1e30f;
        for (int c = 0; c < 10; ++c) m = fmaxf(m, lg[t * 10 + c]);
        float s = 0.f;
        for (int c = 0; c < 10; ++c) s += expf(lg[t * 10 + c] - m);
        float ls = logf(s);
        for (int c = 0; c < 10; ++c)
            out[(mb * 64 + t) * 10 + c] = lg[t * 10 + c] - m - ls;
    }
}

// ---------------------------------------------------------------------------
extern "C" void kernel_launch(void* const* d_in, const int* in_sizes, int n_in,
                              void* d_out, int out_size, void* d_ws, size_t ws_size,
                              hipStream_t stream) {
    const float* x   = (const float*)d_in[0];
    const float* w1  = (const float*)d_in[1];
    const float* b1  = (const float*)d_in[2];
    const float* w2  = (const float*)d_in[3];
    const float* b2  = (const float*)d_in[4];
    const float* w3  = (const float*)d_in[5];
    const float* b3  = (const float*)d_in[6];
    const float* fw1 = (const float*)d_in[7];
    const float* fb1 = (const float*)d_in[8];
    const float* fw2 = (const float*)d_in[9];
    const float* fb2 = (const float*)d_in[10];
    float* out = (float*)d_out;

    // ws layout (4-byte units): ~63 MB
    const size_t PFL  = (size_t)2048 * 6272;     // pflat (u16 pairs as u32)
    const size_t PART = (size_t)8 * 2048 * 128;
    const size_t WA2 = 9216, WA3 = 18432, WP1 = (size_t)128 * 6272;

    u32* ws = (u32*)d_ws;
    u32* pflat  = ws;
    float* part = (float*)(pflat + PFL);
    u32* wA2    = (u32*)(part + PART);
    u32* wA3    = wA2 + WA2;
    u32* wp1    = wA3 + WA3;

    const int n_pack = (int)(WA2 + WA3 + WP1);
    k_pack<<<(n_pack + 255) / 256, 256, 0, stream>>>(w2, w3, fw1, wA2, wA3, wp1);
    k_net<<<2048, 256, 0, stream>>>(x, w1, b1, wA2, b2, wA3, b3, pflat);
    k_fc1<<<dim3(32, 8), 256, 0, stream>>>(pflat, wp1, part);
    k_fc2<<<32, 256, 0, stream>>>(part, fb1, fw2, fb2, out);
}

// Round 12
// 645.982 us; speedup vs baseline: 7.0177x; 2.0799x over previous
//
#include <hip/hip_runtime.h>
#include <hip/hip_bf16.h>

typedef unsigned int u32;
typedef _Float16 h2 __attribute__((ext_vector_type(2)));
typedef _Float16 f16x8 __attribute__((ext_vector_type(8)));
typedef float f32x4 __attribute__((ext_vector_type(4)));
typedef u32 u32x4 __attribute__((ext_vector_type(4)));

__device__ __forceinline__ u32 pk(float a, float b) {
    return __builtin_bit_cast(u32, __builtin_amdgcn_cvt_pkrtz(a, b));
}
__device__ __forceinline__ float lo16(u32 v) { h2 h = __builtin_bit_cast(h2, v); return (float)h[0]; }
__device__ __forceinline__ float hi16(u32 v) { h2 h = __builtin_bit_cast(h2, v); return (float)h[1]; }

// LDS layout (u32 indices)
#define A1O   0        // a1cl [784][16] u32  (conv1 packed ch-last, swizzled)
#define A2O   12544    // a2cl [784][32] u32  (conv2 packed ch-last, swizzled)
#define STO   37648    // stats 128 f32
#define SB2O  37776    // bias2 64 f32
#define SB3O  37840    // bias3 64 f32
#define SMEMSZ 37904   // 151,616 B

// ---------------------------------------------------------------------------
// k_pack: weights into MFMA A-fragment order + FC1 f16 pairs.
// wA2[(mt*9+ks)*64+l][r]: A[oc=mt*16+(l&15)][k=ks*32+(l>>4)*8+2r(+1)]
// wA3[(mt*18+ks)*64+l][r]: tap=ks>>1, ic=(ks&1)*32+(l>>4)*8+2r(+1)
// wp1[row][u]: pairs (2u,2u+1) of flattened fw1 row.
// ---------------------------------------------------------------------------
__global__ __launch_bounds__(256) void k_pack(const float* __restrict__ w2,
                                              const float* __restrict__ w3,
                                              const float* __restrict__ fw1,
                                              u32* wA2, u32* wA3, u32* wp1) {
    int i = blockIdx.x * 256 + threadIdx.x;
    const int n1 = 9216, n2 = 18432, n3 = 128 * 6272;
    if (i < n1) {
        int r = i & 3, l = (i >> 2) & 63, t2 = i >> 8;   // t2 = mt*9+ks
        int ks = t2 % 9, mt = t2 / 9;
        int oc = mt * 16 + (l & 15);
        int ic = (l >> 4) * 8 + 2 * r;
        wA2[i] = pk(w2[(oc * 32 + ic) * 9 + ks], w2[(oc * 32 + ic + 1) * 9 + ks]);
    } else if (i < n1 + n2) {
        int j = i - n1;
        int r = j & 3, l = (j >> 2) & 63, t2 = j >> 8;   // t2 = mt*18+ks
        int ks = t2 % 18, mt = t2 / 18;
        int oc = mt * 16 + (l & 15);
        int ic = (ks & 1) * 32 + (l >> 4) * 8 + 2 * r;
        int tap = ks >> 1;
        wA3[j] = pk(w3[(oc * 64 + ic) * 9 + tap], w3[(oc * 64 + ic + 1) * 9 + tap]);
    } else if (i < n1 + n2 + n3) {
        int j = i - n1 - n2;
        int row = j / 6272, u = j % 6272;
        wp1[j] = pk(fw1[row * 12544 + 2 * u], fw1[row * 12544 + 2 * u + 1]);
    }
}

// ---------------------------------------------------------------------------
// Fused net1, 1024 threads (16 waves = 4/SIMD under the 1-block LDS cap).
// Output u16 f16 at flatten order k = oc*196 + r*14 + px.
// ---------------------------------------------------------------------------
__global__ __launch_bounds__(1024) void k_net(const float* __restrict__ x,
                                              const float* __restrict__ w1,
                                              const float* __restrict__ b1,
                                              const u32* __restrict__ wA2,
                                              const float* __restrict__ b2,
                                              const u32* __restrict__ wA3,
                                              const float* __restrict__ b3,
                                              u32* __restrict__ pflat) {
    __shared__ u32 smem[SMEMSZ];
    u32* a1 = smem + A1O;
    u32* a2 = smem + A2O;
    float* st  = (float*)(smem + STO);
    float* sb2 = (float*)(smem + SB2O);
    float* sb3 = (float*)(smem + SB3O);
    float* xs  = (float*)(smem + A1O);     // 900 f32, early phase only
    float* c1f = (float*)(smem + A2O);     // 32*784 f32, early phase only

    const int b = blockIdx.x, t = threadIdx.x;
    const int wv = t >> 6, l = t & 63;
    const int xi = l & 15, kg = l >> 4;

    // ---- phase 0: biases + zero padded input
    if (t < 64) { sb2[t] = b2[t]; sb3[t] = b3[t]; }
    for (int i = t; i < 900; i += 1024) xs[i] = 0.f;
    __syncthreads();
    // ---- phase 1: stage input
    const float* xb = x + b * 784;
    for (int i = t; i < 784; i += 1024) xs[(i / 28 + 1) * 30 + (i % 28) + 1] = xb[i];
    __syncthreads();
    // ---- phase 2: conv1 (VALU, flattened over oc*p)
    for (int i = t; i < 25088; i += 1024) {
        int oc = i / 784, p = i - oc * 784;
        const float* base = &xs[(p / 28) * 30 + (p % 28)];
        float acc = b1[oc];
        const float* w = &w1[oc * 9];
#pragma unroll
        for (int r = 0; r < 3; ++r)
#pragma unroll
            for (int c = 0; c < 3; ++c) acc += base[r * 30 + c] * w[3 * r + c];
        c1f[i] = acc;
    }
    __syncthreads();
    // ---- phase 3: conv1 IN stats (32 ch over 16 waves)
    for (int oc = wv; oc < 32; oc += 16) {
        float s = 0.f, s2 = 0.f;
        for (int p = l; p < 784; p += 64) { float v = c1f[oc * 784 + p]; s += v; s2 += v * v; }
#pragma unroll
        for (int off = 32; off; off >>= 1) { s += __shfl_xor(s, off); s2 += __shfl_xor(s2, off); }
        if (l == 0) {
            float mu = s * (1.f / 784.f);
            float var = s2 * (1.f / 784.f) - mu * mu;
            st[2 * oc] = mu; st[2 * oc + 1] = rsqrtf(var + 1e-5f);
        }
    }
    __syncthreads();
    // ---- phase 4: normalize+relu+pack -> a1cl[p*16 + (cp ^ sw1(p))]
    for (int i = t; i < 12544; i += 1024) {
        int cp = i / 784, p = i - cp * 784;
        float f0 = (c1f[(2 * cp) * 784 + p]     - st[4 * cp])     * st[4 * cp + 1];
        float f1 = (c1f[(2 * cp + 1) * 784 + p] - st[4 * cp + 2]) * st[4 * cp + 3];
        a1[p * 16 + (cp ^ (((p >> 1) & 3) << 2))] = pk(fmaxf(f0, 0.f), fmaxf(f1, 0.f));
    }
    __syncthreads();

    // ---- phase 5: conv2 MFMA. 56 units (y,half) over 16 waves.
    for (int j = 0; j < 4; ++j) {
        int nt = wv + 16 * j;
        if (nt >= 56) break;
        int y = nt >> 1, hs = nt & 1;
        f32x4 acc[4];
#pragma unroll
        for (int mt = 0; mt < 4; ++mt)
#pragma unroll
            for (int r = 0; r < 4; ++r) acc[mt][r] = sb2[mt * 16 + kg * 4 + r];
#pragma unroll 2
        for (int ks = 0; ks < 9; ++ks) {
            int dy = ks / 3, dx = ks % 3;
            int yy = y + dy - 1;
            if ((unsigned)yy >= 28u) continue;
            int xx = hs * 16 + xi + dx - 1;
            int ax = xx < 0 ? 0 : (xx > 27 ? 27 : xx);
            int pp = yy * 28 + ax;
            u32x4 bv = *(const u32x4*)&a1[pp * 16 + ((kg * 4) ^ (((pp >> 1) & 3) << 2))];
            u32x4 z = {0u, 0u, 0u, 0u};
            bv = ((unsigned)xx < 28u) ? bv : z;
#pragma unroll
            for (int mt = 0; mt < 4; ++mt) {
                u32x4 av = *(const u32x4*)(wA2 + (((mt * 9 + ks) * 64 + l) << 2));
                acc[mt] = __builtin_amdgcn_mfma_f32_16x16x32_f16(
                    __builtin_bit_cast(f16x8, av),
                    __builtin_bit_cast(f16x8, bv), acc[mt], 0, 0, 0);
            }
        }
        int xx = hs * 16 + xi;
        if (xx < 28) {
            int p = y * 28 + xx;
            int sw = (p & 7) << 2;
#pragma unroll
            for (int mt = 0; mt < 4; ++mt) {
                int cp0 = mt * 8 + kg * 2;
                a2[p * 32 + (cp0 ^ sw)]       = pk(acc[mt][0], acc[mt][1]);
                a2[p * 32 + ((cp0 + 1) ^ sw)] = pk(acc[mt][2], acc[mt][3]);
            }
        }
    }
    __syncthreads();
    // ---- phase 6: conv2 IN stats (64 ch over 16 waves)
    for (int ch = wv; ch < 64; ch += 16) {
        float s = 0.f, s2 = 0.f;
        int cp = ch >> 1, hi = ch & 1;
        for (int p = l; p < 784; p += 64) {
            u32 v = a2[p * 32 + (cp ^ ((p & 7) << 2))];
            float f = hi ? hi16(v) : lo16(v);
            s += f; s2 += f * f;
        }
#pragma unroll
        for (int off = 32; off; off >>= 1) { s += __shfl_xor(s, off); s2 += __shfl_xor(s2, off); }
        if (l == 0) {
            float mu = s * (1.f / 784.f);
            float var = s2 * (1.f / 784.f) - mu * mu;
            st[2 * ch] = mu; st[2 * ch + 1] = rsqrtf(var + 1e-5f);
        }
    }
    __syncthreads();
    // ---- phase 7: normalize a2cl in place (no relu)
    for (int i = t; i < 25088; i += 1024) {
        int p = i >> 5, cp = i & 31;
        int idx = p * 32 + (cp ^ ((p & 7) << 2));
        u32 v = a2[idx];
        a2[idx] = pk((lo16(v) - st[4 * cp]) * st[4 * cp + 1],
                     (hi16(v) - st[4 * cp + 2]) * st[4 * cp + 3]);
    }
    __syncthreads();

    // ---- phase 8: conv3 MFMA. 56 units (pr 0..27, mh 0..1) over 16 waves.
    {
        unsigned short* dstp = (unsigned short*)pflat;
        for (int j = 0; j < 4; ++j) {
            int nt = wv + 16 * j;
            if (nt >= 56) break;
            int pr = nt >> 1, mh = nt & 1;
            int r2 = pr >> 1, hh = pr & 1;
            f32x4 acc[2][2];
#pragma unroll
            for (int sub = 0; sub < 2; ++sub)
#pragma unroll
                for (int mtl = 0; mtl < 2; ++mtl)
#pragma unroll
                    for (int rr = 0; rr < 4; ++rr)
                        acc[sub][mtl][rr] = sb3[(mh * 2 + mtl) * 16 + kg * 4 + rr];
#pragma unroll 2
            for (int ks = 0; ks < 18; ++ks) {
                int tap = ks >> 1, kh = ks & 1;
                int dy = tap / 3, dx = tap % 3;
                int xx = hh * 16 + xi + dx - 1;
                int ax = xx < 0 ? 0 : (xx > 27 ? 27 : xx);
                bool mk = (unsigned)xx < 28u;
                u32x4 av[2];
#pragma unroll
                for (int mtl = 0; mtl < 2; ++mtl)
                    av[mtl] = *(const u32x4*)(wA3 + ((((mh * 2 + mtl) * 18 + ks) * 64 + l) << 2));
#pragma unroll
                for (int sub = 0; sub < 2; ++sub) {
                    int yy = 2 * r2 + sub + dy - 1;
                    if ((unsigned)yy >= 28u) continue;
                    int pp = yy * 28 + ax;
                    u32x4 bv = *(const u32x4*)&a2[pp * 32 + ((kh * 16 + kg * 4) ^ ((pp & 7) << 2))];
                    u32x4 z = {0u, 0u, 0u, 0u};
                    bv = mk ? bv : z;
#pragma unroll
                    for (int mtl = 0; mtl < 2; ++mtl)
                        acc[sub][mtl] = __builtin_amdgcn_mfma_f32_16x16x32_f16(
                            __builtin_bit_cast(f16x8, av[mtl]),
                            __builtin_bit_cast(f16x8, bv), acc[sub][mtl], 0, 0, 0);
                }
            }
#pragma unroll
            for (int mtl = 0; mtl < 2; ++mtl)
#pragma unroll
                for (int rr = 0; rr < 4; ++rr) {
                    float v = fmaxf(acc[0][mtl][rr], acc[1][mtl][rr]);
                    v = fmaxf(v, 0.f);
                    float partner = __shfl_xor(v, 1);
                    float hx = fmaxf(v, partner);
                    int xx = hh * 16 + xi;
                    if ((xi & 1) == 0 && xx < 28) {
                        int px = xx >> 1;
                        int oc = (mh * 2 + mtl) * 16 + kg * 4 + rr;
                        dstp[b * 12544 + oc * 196 + r2 * 14 + px] =
                            __builtin_bit_cast(unsigned short, (_Float16)hx);
                    }
                }
        }
    }
}

// ---------------------------------------------------------------------------
// Fused FC1 (MFMA, direct-from-global fragments) + FC2 + log_softmax.
// Block = 16 images, 512 threads = 8 waves, 8-way K-split (49 k-steps each).
// ---------------------------------------------------------------------------
__global__ __launch_bounds__(512) void k_fc(const u32* __restrict__ pflat,
                                            const u32* __restrict__ wp1,
                                            const float* __restrict__ fb1,
                                            const float* __restrict__ fw2,
                                            const float* __restrict__ fb2,
                                            float* __restrict__ out) {
    __shared__ float ph[8 * 128 * 16];   // 64 KB partials
    __shared__ float hbuf[16 * 129];     // padded h
    __shared__ float lg[160];
    const int t = threadIdx.x, wv = t >> 6, l = t & 63;
    const int xi = l & 15, kg = l >> 4;
    const int img0 = blockIdx.x * 16;

    f32x4 acc[8];
#pragma unroll
    for (int mt = 0; mt < 8; ++mt)
#pragma unroll
        for (int r = 0; r < 4; ++r) acc[mt][r] = 0.f;

    const u32* bbase = pflat + (size_t)(img0 + xi) * 6272;
#pragma unroll 2
    for (int kk = 0; kk < 49; ++kk) {
        int koff = (wv * 49 + kk) * 16 + kg * 4;
        u32x4 bv = *(const u32x4*)(bbase + koff);
#pragma unroll
        for (int mt = 0; mt < 8; ++mt) {
            u32x4 av = *(const u32x4*)(wp1 + (size_t)(mt * 16 + xi) * 6272 + koff);
            acc[mt] = __builtin_amdgcn_mfma_f32_16x16x32_f16(
                __builtin_bit_cast(f16x8, av),
                __builtin_bit_cast(f16x8, bv), acc[mt], 0, 0, 0);
        }
    }
    // partials: lane holds D[out=mt*16+kg*4+r][img=xi]
#pragma unroll
    for (int mt = 0; mt < 8; ++mt)
#pragma unroll
        for (int r = 0; r < 4; ++r)
            ph[(wv * 128 + mt * 16 + kg * 4 + r) * 16 + xi] = acc[mt][r];
    __syncthreads();
    // reduce + bias + relu -> hbuf[img][out]
    for (int i = t; i < 2048; i += 512) {
        int o = i >> 4, img = i & 15;
        float s = fb1[o];
#pragma unroll
        for (int w = 0; w < 8; ++w) s += ph[(w * 128 + o) * 16 + img];
        hbuf[img * 129 + o] = s > 0.f ? s : 0.f;
    }
    __syncthreads();
    // FC2
    if (t < 160) {
        int img = t / 10, c = t % 10;
        float s = fb2[c];
        for (int j = 0; j < 128; ++j) s += hbuf[img * 129 + j] * fw2[c * 128 + j];
        lg[t] = s;
    }
    __syncthreads();
    // log_softmax
    if (t < 16) {
        float m = -1e30f;
        for (int c = 0; c < 10; ++c) m = fmaxf(m, lg[t * 10 + c]);
        float s = 0.f;
        for (int c = 0; c < 10; ++c) s += expf(lg[t * 10 + c] - m);
        float ls = logf(s);
        for (int c = 0; c < 10; ++c)
            out[(img0 + t) * 10 + c] = lg[t * 10 + c] - m - ls;
    }
}

// ---------------------------------------------------------------------------
extern "C" void kernel_launch(void* const* d_in, const int* in_sizes, int n_in,
                              void* d_out, int out_size, void* d_ws, size_t ws_size,
                              hipStream_t stream) {
    const float* x   = (const float*)d_in[0];
    const float* w1  = (const float*)d_in[1];
    const float* b1  = (const float*)d_in[2];
    const float* w2  = (const float*)d_in[3];
    const float* b2  = (const float*)d_in[4];
    const float* w3  = (const float*)d_in[5];
    const float* b3  = (const float*)d_in[6];
    const float* fw1 = (const float*)d_in[7];
    const float* fb1 = (const float*)d_in[8];
    const float* fw2 = (const float*)d_in[9];
    const float* fb2 = (const float*)d_in[10];
    float* out = (float*)d_out;

    // ws layout (4-byte units): ~55 MB
    const size_t PFL = (size_t)2048 * 6272;      // pflat (u16 pairs as u32)
    const size_t WA2 = 9216, WA3 = 18432, WP1 = (size_t)128 * 6272;

    u32* ws = (u32*)d_ws;
    u32* pflat = ws;
    u32* wA2   = pflat + PFL;
    u32* wA3   = wA2 + WA2;
    u32* wp1   = wA3 + WA3;

    const int n_pack = (int)(WA2 + WA3 + WP1);
    k_pack<<<(n_pack + 255) / 256, 256, 0, stream>>>(w2, w3, fw1, wA2, wA3, wp1);
    k_net<<<2048, 1024, 0, stream>>>(x, w1, b1, wA2, b2, wA3, b3, pflat);
    k_fc<<<128, 512, 0, stream>>>(pflat, wp1, fb1, fw2, fb2, out);
}

// Round 14
// 587.674 us; speedup vs baseline: 7.7140x; 1.0992x over previous
//
#include <hip/hip_runtime.h>
#include <hip/hip_bf16.h>

typedef unsigned int u32;
typedef _Float16 h2 __attribute__((ext_vector_type(2)));
typedef _Float16 f16x8 __attribute__((ext_vector_type(8)));
typedef float f32x4 __attribute__((ext_vector_type(4)));
typedef u32 u32x4 __attribute__((ext_vector_type(4)));

__device__ __forceinline__ u32 pk(float a, float b) {
    return __builtin_bit_cast(u32, __builtin_amdgcn_cvt_pkrtz(a, b));
}
__device__ __forceinline__ float lo16(u32 v) { h2 h = __builtin_bit_cast(h2, v); return (float)h[0]; }
__device__ __forceinline__ float hi16(u32 v) { h2 h = __builtin_bit_cast(h2, v); return (float)h[1]; }

// LDS layout (u32 indices)
#define A1O   0        // a1cl [784][16] u32 (conv1 pairs, swizzled)
#define A2O   12544    // a2cl [784][32] u32 (conv2 pairs, swizzled); xs f32 early
#define STO   37648    // stats 128 f32
#define SB2O  37776    // bias2 64 f32
#define SB3O  37840    // bias3 64 f32
#define SMEMSZ 37904   // 151,616 B

// ---------------------------------------------------------------------------
// k_pack: weights into MFMA A-fragment order + FC1 f16 pairs. (unchanged)
// ---------------------------------------------------------------------------
__global__ __launch_bounds__(256) void k_pack(const float* __restrict__ w2,
                                              const float* __restrict__ w3,
                                              const float* __restrict__ fw1,
                                              u32* wA2, u32* wA3, u32* wp1) {
    int i = blockIdx.x * 256 + threadIdx.x;
    const int n1 = 9216, n2 = 18432, n3 = 128 * 6272;
    if (i < n1) {
        int r = i & 3, l = (i >> 2) & 63, t2 = i >> 8;
        int ks = t2 % 9, mt = t2 / 9;
        int oc = mt * 16 + (l & 15);
        int ic = (l >> 4) * 8 + 2 * r;
        wA2[i] = pk(w2[(oc * 32 + ic) * 9 + ks], w2[(oc * 32 + ic + 1) * 9 + ks]);
    } else if (i < n1 + n2) {
        int j = i - n1;
        int r = j & 3, l = (j >> 2) & 63, t2 = j >> 8;
        int ks = t2 % 18, mt = t2 / 18;
        int oc = mt * 16 + (l & 15);
        int ic = (ks & 1) * 32 + (l >> 4) * 8 + 2 * r;
        int tap = ks >> 1;
        wA3[j] = pk(w3[(oc * 64 + ic) * 9 + tap], w3[(oc * 64 + ic + 1) * 9 + tap]);
    } else if (i < n1 + n2 + n3) {
        int j = i - n1 - n2;
        int row = j / 6272, u = j % 6272;
        wp1[j] = pk(fw1[row * 12544 + 2 * u], fw1[row * 12544 + 2 * u + 1]);
    }
}

// ---------------------------------------------------------------------------
// Fused net1, 1024 threads. Output u16 f16 at flatten k = oc*196 + r*14 + px.
// ---------------------------------------------------------------------------
__global__ __launch_bounds__(1024) void k_net(const float* __restrict__ x,
                                              const float* __restrict__ w1,
                                              const float* __restrict__ b1,
                                              const u32* __restrict__ wA2,
                                              const float* __restrict__ b2,
                                              const u32* __restrict__ wA3,
                                              const float* __restrict__ b3,
                                              u32* __restrict__ pflat) {
    __shared__ u32 smem[SMEMSZ];
    u32* a1 = smem + A1O;
    u32* a2 = smem + A2O;
    float* st  = (float*)(smem + STO);
    float* sb2 = (float*)(smem + SB2O);
    float* sb3 = (float*)(smem + SB3O);
    float* xs  = (float*)(smem + A2O);     // 900 f32, early phase only (a2 region)

    const int b = blockIdx.x, t = threadIdx.x;
    const int wv = t >> 6, l = t & 63;
    const int xi = l & 15, kg = l >> 4;

    // ---- phase 0: biases + zero padded input
    if (t < 64) { sb2[t] = b2[t]; sb3[t] = b3[t]; }
    for (int i = t; i < 900; i += 1024) xs[i] = 0.f;
    __syncthreads();
    // ---- phase 1: stage input
    const float* xb = x + b * 784;
    for (int i = t; i < 784; i += 1024) xs[(i / 28 + 1) * 30 + (i % 28) + 1] = xb[i];
    __syncthreads();
    // ---- phase 2: conv1, thread-per-pixel, 9 regs read once, all 32 oc.
    // Writes RAW (pre-norm) f16 pairs direct to a1cl.
    if (t < 784) {
        int p = t;
        const float* base = &xs[(p / 28) * 30 + (p % 28)];
        float rx[9];
#pragma unroll
        for (int r = 0; r < 3; ++r)
#pragma unroll
            for (int c = 0; c < 3; ++c) rx[r * 3 + c] = base[r * 30 + c];
        int sw = ((p >> 1) & 3) << 2;
#pragma unroll 4
        for (int cp = 0; cp < 16; ++cp) {
            float s0 = b1[2 * cp], s1 = b1[2 * cp + 1];
#pragma unroll
            for (int k = 0; k < 9; ++k) {
                s0 += rx[k] * w1[(2 * cp) * 9 + k];
                s1 += rx[k] * w1[(2 * cp + 1) * 9 + k];
            }
            a1[p * 16 + (cp ^ sw)] = pk(s0, s1);
        }
    }
    __syncthreads();
    // ---- phase 3: conv1 IN stats from pairs (16 cps over 16 waves)
    {
        int cp = wv;
        float s0 = 0.f, q0 = 0.f, s1 = 0.f, q1 = 0.f;
        for (int p = l; p < 784; p += 64) {
            u32 v = a1[p * 16 + (cp ^ (((p >> 1) & 3) << 2))];
            float f0 = lo16(v), f1 = hi16(v);
            s0 += f0; q0 += f0 * f0; s1 += f1; q1 += f1 * f1;
        }
#pragma unroll
        for (int off = 32; off; off >>= 1) {
            s0 += __shfl_xor(s0, off); q0 += __shfl_xor(q0, off);
            s1 += __shfl_xor(s1, off); q1 += __shfl_xor(q1, off);
        }
        if (l == 0) {
            float mu0 = s0 * (1.f / 784.f), mu1 = s1 * (1.f / 784.f);
            st[4 * cp + 0] = mu0;
            st[4 * cp + 1] = rsqrtf(q0 * (1.f / 784.f) - mu0 * mu0 + 1e-5f);
            st[4 * cp + 2] = mu1;
            st[4 * cp + 3] = rsqrtf(q1 * (1.f / 784.f) - mu1 * mu1 + 1e-5f);
        }
    }
    __syncthreads();
    // ---- phase 4: normalize+relu a1 in place (cp invariant -> hoisted stats)
    {
        int cp = (t & 15) ^ (((t >> 5) & 3) << 2);
        float mu0 = st[4 * cp], ri0 = st[4 * cp + 1];
        float mu1 = st[4 * cp + 2], ri1 = st[4 * cp + 3];
        for (int i = t; i < 12544; i += 1024) {
            u32 v = a1[i];
            a1[i] = pk(fmaxf((lo16(v) - mu0) * ri0, 0.f),
                       fmaxf((hi16(v) - mu1) * ri1, 0.f));
        }
    }
    __syncthreads();

    // ---- phase 5: conv2 MFMA. 56 units (y,half) over 16 waves. (unchanged)
    for (int j = 0; j < 4; ++j) {
        int nt = wv + 16 * j;
        if (nt >= 56) break;
        int y = nt >> 1, hs = nt & 1;
        f32x4 acc[4];
#pragma unroll
        for (int mt = 0; mt < 4; ++mt)
#pragma unroll
            for (int r = 0; r < 4; ++r) acc[mt][r] = sb2[mt * 16 + kg * 4 + r];
#pragma unroll 2
        for (int ks = 0; ks < 9; ++ks) {
            int dy = ks / 3, dx = ks % 3;
            int yy = y + dy - 1;
            if ((unsigned)yy >= 28u) continue;
            int xx = hs * 16 + xi + dx - 1;
            int ax = xx < 0 ? 0 : (xx > 27 ? 27 : xx);
            int pp = yy * 28 + ax;
            u32x4 bv = *(const u32x4*)&a1[pp * 16 + ((kg * 4) ^ (((pp >> 1) & 3) << 2))];
            u32x4 z = {0u, 0u, 0u, 0u};
            bv = ((unsigned)xx < 28u) ? bv : z;
#pragma unroll
            for (int mt = 0; mt < 4; ++mt) {
                u32x4 av = *(const u32x4*)(wA2 + (((mt * 9 + ks) * 64 + l) << 2));
                acc[mt] = __builtin_amdgcn_mfma_f32_16x16x32_f16(
                    __builtin_bit_cast(f16x8, av),
                    __builtin_bit_cast(f16x8, bv), acc[mt], 0, 0, 0);
            }
        }
        int xx = hs * 16 + xi;
        if (xx < 28) {
            int p = y * 28 + xx;
            int sw = (p & 7) << 2;
#pragma unroll
            for (int mt = 0; mt < 4; ++mt) {
                int cp0 = mt * 8 + kg * 2;
                a2[p * 32 + (cp0 ^ sw)]       = pk(acc[mt][0], acc[mt][1]);
                a2[p * 32 + ((cp0 + 1) ^ sw)] = pk(acc[mt][2], acc[mt][3]);
            }
        }
    }
    __syncthreads();
    // ---- phase 6: conv2 IN stats, pair-dedup (32 cps over 16 waves)
    for (int cp = wv; cp < 32; cp += 16) {
        float s0 = 0.f, q0 = 0.f, s1 = 0.f, q1 = 0.f;
        for (int p = l; p < 784; p += 64) {
            u32 v = a2[p * 32 + (cp ^ ((p & 7) << 2))];
            float f0 = lo16(v), f1 = hi16(v);
            s0 += f0; q0 += f0 * f0; s1 += f1; q1 += f1 * f1;
        }
#pragma unroll
        for (int off = 32; off; off >>= 1) {
            s0 += __shfl_xor(s0, off); q0 += __shfl_xor(q0, off);
            s1 += __shfl_xor(s1, off); q1 += __shfl_xor(q1, off);
        }
        if (l == 0) {
            float mu0 = s0 * (1.f / 784.f), mu1 = s1 * (1.f / 784.f);
            st[4 * cp + 0] = mu0;
            st[4 * cp + 1] = rsqrtf(q0 * (1.f / 784.f) - mu0 * mu0 + 1e-5f);
            st[4 * cp + 2] = mu1;
            st[4 * cp + 3] = rsqrtf(q1 * (1.f / 784.f) - mu1 * mu1 + 1e-5f);
        }
    }
    __syncthreads();
    // ---- phase 7: normalize a2 in place (cp invariant -> hoisted stats)
    {
        int cp = (t & 31) ^ (((t >> 5) & 7) << 2);
        float mu0 = st[4 * cp], ri0 = st[4 * cp + 1];
        float mu1 = st[4 * cp + 2], ri1 = st[4 * cp + 3];
        for (int i = t; i < 25088; i += 1024) {
            u32 v = a2[i];
            a2[i] = pk((lo16(v) - mu0) * ri0, (hi16(v) - mu1) * ri1);
        }
    }
    __syncthreads();

    // ---- phase 8: conv3 MFMA. 28 units (row-pair r2, half hh), full M=64,
    // 4-row B cache shared across pool sub-rows. relu+maxpool -> u16 stores.
    {
        unsigned short* dstp = (unsigned short*)pflat;
        for (int j = 0; j < 2; ++j) {
            int u = wv + 16 * j;
            if (u >= 28) break;
            int r2 = u >> 1, hh = u & 1;
            f32x4 acc[2][4];
#pragma unroll
            for (int sub = 0; sub < 2; ++sub)
#pragma unroll
                for (int mtl = 0; mtl < 4; ++mtl)
#pragma unroll
                    for (int rr = 0; rr < 4; ++rr)
                        acc[sub][mtl][rr] = sb3[mtl * 16 + kg * 4 + rr];
#pragma unroll 1
            for (int dx = 0; dx < 3; ++dx) {
                int xx = hh * 16 + xi + dx - 1;
                int ax = xx < 0 ? 0 : (xx > 27 ? 27 : xx);
                bool mk = (unsigned)xx < 28u;
#pragma unroll
                for (int kh = 0; kh < 2; ++kh) {
                    u32x4 bvr[4];
#pragma unroll
                    for (int rr = 0; rr < 4; ++rr) {
                        int yy = 2 * r2 - 1 + rr;
                        u32x4 z = {0u, 0u, 0u, 0u};
                        bvr[rr] = z;
                        if (((unsigned)yy < 28u) && mk) {
                            int pp = yy * 28 + ax;
                            bvr[rr] = *(const u32x4*)&a2[pp * 32 +
                                        ((kh * 16 + kg * 4) ^ ((pp & 7) << 2))];
                        }
                    }
#pragma unroll
                    for (int dy = 0; dy < 3; ++dy) {
                        int ks = (dy * 3 + dx) * 2 + kh;
#pragma unroll
                        for (int mtl = 0; mtl < 4; ++mtl) {
                            u32x4 av = *(const u32x4*)(wA3 + (((mtl * 18 + ks) * 64 + l) << 2));
                            acc[0][mtl] = __builtin_amdgcn_mfma_f32_16x16x32_f16(
                                __builtin_bit_cast(f16x8, av),
                                __builtin_bit_cast(f16x8, bvr[dy]), acc[0][mtl], 0, 0, 0);
                            acc[1][mtl] = __builtin_amdgcn_mfma_f32_16x16x32_f16(
                                __builtin_bit_cast(f16x8, av),
                                __builtin_bit_cast(f16x8, bvr[dy + 1]), acc[1][mtl], 0, 0, 0);
                        }
                    }
                }
            }
#pragma unroll
            for (int mtl = 0; mtl < 4; ++mtl)
#pragma unroll
                for (int rr = 0; rr < 4; ++rr) {
                    float v = fmaxf(acc[0][mtl][rr], acc[1][mtl][rr]);
                    v = fmaxf(v, 0.f);
                    float partner = __shfl_xor(v, 1);
                    float hx = fmaxf(v, partner);
                    int xx = hh * 16 + xi;
                    if ((xi & 1) == 0 && xx < 28) {
                        int px = xx >> 1;
                        int oc = mtl * 16 + kg * 4 + rr;
                        dstp[b * 12544 + oc * 196 + r2 * 14 + px] =
                            __builtin_bit_cast(unsigned short, (_Float16)hx);
                    }
                }
        }
    }
}

// ---------------------------------------------------------------------------
// Fused FC1 (MFMA) + FC2 + log_softmax. Block = 8 images, 512 thr = 8 waves,
// 8-way K-split. 256 blocks -> all CUs.
// ---------------------------------------------------------------------------
__global__ __launch_bounds__(512) void k_fc(const u32* __restrict__ pflat,
                                            const u32* __restrict__ wp1,
                                            const float* __restrict__ fb1,
                                            const float* __restrict__ fw2,
                                            const float* __restrict__ fb2,
                                            float* __restrict__ out) {
    __shared__ float ph[8 * 128 * 8];    // 32 KB partials
    __shared__ float hbuf[8 * 129];
    __shared__ float lg[80];
    const int t = threadIdx.x, wv = t >> 6, l = t & 63;
    const int xi = l & 15, kg = l >> 4;
    const int img0 = blockIdx.x * 8;

    f32x4 acc[8];
#pragma unroll
    for (int mt = 0; mt < 8; ++mt)
#pragma unroll
        for (int r = 0; r < 4; ++r) acc[mt][r] = 0.f;

    const u32* bbase = pflat + (size_t)(img0 + (xi & 7)) * 6272;
#pragma unroll 2
    for (int kk = 0; kk < 49; ++kk) {
        int koff = (wv * 49 + kk) * 16 + kg * 4;
        u32x4 bv = *(const u32x4*)(bbase + koff);
#pragma unroll
        for (int mt = 0; mt < 8; ++mt) {
            u32x4 av = *(const u32x4*)(wp1 + (size_t)(mt * 16 + xi) * 6272 + koff);
            acc[mt] = __builtin_amdgcn_mfma_f32_16x16x32_f16(
                __builtin_bit_cast(f16x8, av),
                __builtin_bit_cast(f16x8, bv), acc[mt], 0, 0, 0);
        }
    }
    if (xi < 8) {
#pragma unroll
        for (int mt = 0; mt < 8; ++mt)
#pragma unroll
            for (int r = 0; r < 4; ++r)
                ph[(wv * 128 + mt * 16 + kg * 4 + r) * 8 + xi] = acc[mt][r];
    }
    __syncthreads();
    for (int i = t; i < 1024; i += 512) {
        int o = i >> 3, img = i & 7;
        float s = fb1[o];
#pragma unroll
        for (int w = 0; w < 8; ++w) s += ph[(w * 128 + o) * 8 + img];
        hbuf[img * 129 + o] = s > 0.f ? s : 0.f;
    }
    __syncthreads();
    if (t < 80) {
        int img = t / 10, c = t % 10;
        float s = fb2[c];
        for (int j = 0; j < 128; ++j) s += hbuf[img * 129 + j] * fw2[c * 128 + j];
        lg[t] = s;
    }
    __syncthreads();
    if (t < 8) {
        float m = -1e30f;
        for (int c = 0; c < 10; ++c) m = fmaxf(m, lg[t * 10 + c]);
        float s = 0.f;
        for (int c = 0; c < 10; ++c) s += expf(lg[t * 10 + c] - m);
        float ls = logf(s);
        for (int c = 0; c < 10; ++c)
            out[(img0 + t) * 10 + c] = lg[t * 10 + c] - m - ls;
    }
}

// ---------------------------------------------------------------------------
extern "C" void kernel_launch(void* const* d_in, const int* in_sizes, int n_in,
                              void* d_out, int out_size, void* d_ws, size_t ws_size,
                              hipStream_t stream) {
    const float* x   = (const float*)d_in[0];
    const float* w1  = (const float*)d_in[1];
    const float* b1  = (const float*)d_in[2];
    const float* w2  = (const float*)d_in[3];
    const float* b2  = (const float*)d_in[4];
    const float* w3  = (const float*)d_in[5];
    const float* b3  = (const float*)d_in[6];
    const float* fw1 = (const float*)d_in[7];
    const float* fb1 = (const float*)d_in[8];
    const float* fw2 = (const float*)d_in[9];
    const float* fb2 = (const float*)d_in[10];
    float* out = (float*)d_out;

    const size_t PFL = (size_t)2048 * 6272;
    const size_t WA2 = 9216, WA3 = 18432, WP1 = (size_t)128 * 6272;

    u32* ws = (u32*)d_ws;
    u32* pflat = ws;
    u32* wA2   = pflat + PFL;
    u32* wA3   = wA2 + WA2;
    u32* wp1   = wA3 + WA3;

    const int n_pack = (int)(WA2 + WA3 + WP1);
    k_pack<<<(n_pack + 255) / 256, 256, 0, stream>>>(w2, w3, fw1, wA2, wA3, wp1);
    k_net<<<2048, 1024, 0, stream>>>(x, w1, b1, wA2, b2, wA3, b3, pflat);
    k_fc<<<256, 512, 0, stream>>>(pflat, wp1, fb1, fw2, fb2, out);
}